// Round 3
// baseline (74.879 us; speedup 1.0000x reference)
//
#include <hip/hip_runtime.h>

// Problem constants (fixed by reference file)
#define IMG 224
#define NP 109                 // (224-8)/2+1 patches per dimension
#define BC 48                  // batch*channels = 16*3
#define NPIX (IMG * IMG)       // 50176
#define TILE 56                // output pixels per tile side (224 = 4*56)
#define QT 28                  // 2x2 quads per tile side
#define PT 31                  // patch rows/cols relevant to one tile
#define XR 68                  // staged x-region rows (56 + 6 halo + 6 over)
#define XC2 34                 // de-interleaved columns actually loaded
#define XCP 36                 // padded row stride for xe/xo (mult of 4 -> b128)
#define RSP 32                 // padded row stride for rs/rt
#define CAP 32                 // padded row stride for ca/cb/cc
#define NTHR 512

// Math: filt zeros DCT coefficients (0,0),(0,1),(1,0) only; D orthonormal =>
// per-patch y = P - c00*D0(x)D0 - c01*D0(x)D1 - c10*D1(x)D0, and the
// scatter-add of P collapses to cnt(h,w)*x[h,w].
//
// R7 change (LDS vectorization): kernel issue count was dominated by scalar
// b32 LDS traffic (P2: 8 reads/16 FMA, P3: 16/24, P4: 12/16, P5: 16/16).
// Row strides padded to multiples of 4 floats so every phase reads/writes
// 16B-aligned float4 (ds_read_b128/ds_write_b128) over 4-wide column groups;
// shifted tap windows (P2/P4) resolved in registers from 8 loaded scalars.
// ~4x fewer LDS instructions, ~1.9x fewer total issues; FMA count unchanged.
// Padding col pc=31 is garbage -> masked with ternary SELECT (never multiply,
// NaN-safe). P1 kept scalar (small share of issues).
//
//   P1 stage x de-interleaved (xe=even cols, xo=odd cols)   [global->LDS]
//   P2 row partials  s(r,pc)=D0.row, t(r,pc)=D1.row         (68x31, shared 4x)
//   P3 patch coefs   c00,c01,c10 from s,t                   (31x31)
//   P4 row-gather    RSe/RSo/RTe/RTo(pr,qw)                 (31x28, shared 4x)
//   P5 quads: combine 4 row-gathers + identity term         (28x28)
// RS* overlays dead rs/rt buffer after P3 (barrier-protected).
//
// CODEGEN RULE (R1): no runtime-indexed private arrays -- all D accesses are
// literal-indexed named scalars via macro unrolling.

#define LOAD_D_SCALARS(D)                                                  \
    const float d0_0 = (D)[0], d0_1 = (D)[1], d0_2 = (D)[2], d0_3 = (D)[3],\
                d0_4 = (D)[4], d0_5 = (D)[5], d0_6 = (D)[6], d0_7 = (D)[7];\
    const float d1_0 = (D)[8],  d1_1 = (D)[9],  d1_2 = (D)[10],            \
                d1_3 = (D)[11], d1_4 = (D)[12], d1_5 = (D)[13],            \
                d1_6 = (D)[14], d1_7 = (D)[15];

// 8-term interleaved dot: x0*q0 + y0*q1 + x1*q2 + y1*q3 + ... + y3*q7
#define DOT8(x0,y0,x1,y1,x2,y2,x3,y3, q0,q1,q2,q3,q4,q5,q6,q7)             \
    fmaf(x0,q0, fmaf(y0,q1, fmaf(x1,q2, fmaf(y1,q3,                        \
    fmaf(x2,q4, fmaf(y2,q5, fmaf(x3,q6, (y3)*(q7))))))))

// LDS layout (floats) -- all offsets multiples of 4 (16B alignment for b128)
#define O_XE   0                       // 68*36 = 2448
#define O_XO   (O_XE + XR * XCP)       // 2448
#define O_RS   (O_XO + XR * XCP)       // 68*32 = 2176
#define O_RT   (O_RS + XR * RSP)       // 2176
#define O_RSE  O_RS                    // overlays rs/rt after P3 (868 each)
#define O_RSO  (O_RSE + PT * QT)
#define O_RTE  (O_RSO + PT * QT)
#define O_RTO  (O_RTE + PT * QT)       // ends 8368 < O_CA, fits in rs+rt
#define O_CA   (O_RT + XR * RSP)       // 31*32 = 992
#define O_CB   (O_CA + PT * CAP)
#define O_CC   (O_CB + PT * CAP)
#define LDS_FLOATS (O_CC + PT * CAP)   // 12224 floats = 48.9 KB

__global__ __launch_bounds__(NTHR) void fused_dct_kernel(
    const float* __restrict__ x, const float* __restrict__ D,
    const float* __restrict__ filt, float* __restrict__ out)
{
    __shared__ __attribute__((aligned(16))) float lds[LDS_FLOATS];
    float* const xe_s = lds + O_XE;
    float* const xo_s = lds + O_XO;
    float* const rs_s = lds + O_RS;
    float* const rt_s = lds + O_RT;
    float* const ca_s = lds + O_CA;
    float* const cb_s = lds + O_CB;
    float* const cc_s = lds + O_CC;
    float* const RSe  = lds + O_RSE;
    float* const RSo  = lds + O_RSO;
    float* const RTe  = lds + O_RTE;
    float* const RTo  = lds + O_RTO;

    const int tid = threadIdx.x;
    const int h0 = blockIdx.y * TILE;
    const int w0 = blockIdx.x * TILE;
    const int bc = blockIdx.z;

    LOAD_D_SCALARS(D)
    const float w00 = 1.0f - filt[0];      // filt[0][0]
    const float w01 = 1.0f - filt[1];      // filt[0][1]
    const float w10 = 1.0f - filt[8];      // filt[1][0]

    const float* xb = x + (size_t)bc * NPIX;

    // ---- P1: stage x rows [h0-6, h0+61], cols [w0-6, w0+61], de-interleaved
    for (int i = tid; i < XR * XC2; i += NTHR) {
        int r  = i / XC2;
        int c2 = i - r * XC2;
        int gr = h0 - 6 + r;
        int gc = w0 - 6 + 2 * c2;              // even => float2-aligned
        float2 v = make_float2(0.f, 0.f);
        if ((unsigned)gr < (unsigned)IMG && (unsigned)gc < (unsigned)IMG)
            v = *(const float2*)(xb + (size_t)gr * IMG + gc);
        xe_s[r * XCP + c2] = v.x;
        xo_s[r * XCP + c2] = v.y;
    }
    __syncthreads();

    // ---- P2: row partials, 4 consecutive pc per item via b128 windows
    // s(pc) = e[pc]d00+o[pc]d01+e[pc+1]d02+o[pc+1]d03+...+o[pc+3]d07
    for (int i = tid; i < XR * 8; i += NTHR) {
        int r = i >> 3, g = i & 7;
        int base = r * XCP + 4 * g;
        float4 E0 = *(const float4*)(xe_s + base);
        float4 E1 = *(const float4*)(xe_s + base + 4);
        float4 O0 = *(const float4*)(xo_s + base);
        float4 O1 = *(const float4*)(xo_s + base + 4);
        float e0=E0.x, e1=E0.y, e2=E0.z, e3=E0.w, e4=E1.x, e5=E1.y, e6=E1.z;
        float o0=O0.x, o1=O0.y, o2=O0.z, o3=O0.w, o4=O1.x, o5=O1.y, o6=O1.z;
        // (g=7: e6/o6 = padding garbage -> feeds only s3/t3 (pc=31), masked in P3)
        float s0 = DOT8(e0,o0,e1,o1,e2,o2,e3,o3, d0_0,d0_1,d0_2,d0_3,d0_4,d0_5,d0_6,d0_7);
        float s1 = DOT8(e1,o1,e2,o2,e3,o3,e4,o4, d0_0,d0_1,d0_2,d0_3,d0_4,d0_5,d0_6,d0_7);
        float s2 = DOT8(e2,o2,e3,o3,e4,o4,e5,o5, d0_0,d0_1,d0_2,d0_3,d0_4,d0_5,d0_6,d0_7);
        float s3 = DOT8(e3,o3,e4,o4,e5,o5,e6,o6, d0_0,d0_1,d0_2,d0_3,d0_4,d0_5,d0_6,d0_7);
        float t0 = DOT8(e0,o0,e1,o1,e2,o2,e3,o3, d1_0,d1_1,d1_2,d1_3,d1_4,d1_5,d1_6,d1_7);
        float t1 = DOT8(e1,o1,e2,o2,e3,o3,e4,o4, d1_0,d1_1,d1_2,d1_3,d1_4,d1_5,d1_6,d1_7);
        float t2 = DOT8(e2,o2,e3,o3,e4,o4,e5,o5, d1_0,d1_1,d1_2,d1_3,d1_4,d1_5,d1_6,d1_7);
        float t3 = DOT8(e3,o3,e4,o4,e5,o5,e6,o6, d1_0,d1_1,d1_2,d1_3,d1_4,d1_5,d1_6,d1_7);
        *(float4*)(rs_s + r * RSP + 4 * g) = make_float4(s0, s1, s2, s3);
        *(float4*)(rt_s + r * RSP + 4 * g) = make_float4(t0, t1, t2, t3);
    }
    __syncthreads();

    // ---- P3: patch coefficients, 4 consecutive pcl per item (b128 rows)
    const int pr0 = (h0 >> 1) - 3;
    const int pc0 = (w0 >> 1) - 3;
    for (int i = tid; i < PT * 8; i += NTHR) {
        int prl = i >> 3, g = i & 7;
        int pcb = 4 * g;
        float c00x=0.f,c00y=0.f,c00z=0.f,c00w=0.f;
        float c01x=0.f,c01y=0.f,c01z=0.f,c01w=0.f;
        float c10x=0.f,c10y=0.f,c10z=0.f,c10w=0.f;
#define P3R(i8)                                                                \
        {                                                                      \
            const float4 S = *(const float4*)(rs_s + (2*prl+(i8))*RSP + pcb);  \
            const float4 T = *(const float4*)(rt_s + (2*prl+(i8))*RSP + pcb);  \
            c00x = fmaf(d0_##i8, S.x, c00x); c00y = fmaf(d0_##i8, S.y, c00y);  \
            c00z = fmaf(d0_##i8, S.z, c00z); c00w = fmaf(d0_##i8, S.w, c00w);  \
            c01x = fmaf(d0_##i8, T.x, c01x); c01y = fmaf(d0_##i8, T.y, c01y);  \
            c01z = fmaf(d0_##i8, T.z, c01z); c01w = fmaf(d0_##i8, T.w, c01w);  \
            c10x = fmaf(d1_##i8, S.x, c10x); c10y = fmaf(d1_##i8, S.y, c10y);  \
            c10z = fmaf(d1_##i8, S.z, c10z); c10w = fmaf(d1_##i8, S.w, c10w);  \
        }
        P3R(0) P3R(1) P3R(2) P3R(3) P3R(4) P3R(5) P3R(6) P3R(7)
#undef P3R
        bool pr_ok = (unsigned)(pr0 + prl) < (unsigned)NP;
        bool v0 = pr_ok && (pcb+0 < PT) && ((unsigned)(pc0+pcb+0) < (unsigned)NP);
        bool v1 = pr_ok && (pcb+1 < PT) && ((unsigned)(pc0+pcb+1) < (unsigned)NP);
        bool v2 = pr_ok && (pcb+2 < PT) && ((unsigned)(pc0+pcb+2) < (unsigned)NP);
        bool v3 = pr_ok && (pcb+3 < PT) && ((unsigned)(pc0+pcb+3) < (unsigned)NP);
        // ternary select (NOT multiply): pc=31 lane may hold NaN garbage
        *(float4*)(ca_s + prl*CAP + pcb) = make_float4(
            v0 ? c00x*w00 : 0.f, v1 ? c00y*w00 : 0.f,
            v2 ? c00z*w00 : 0.f, v3 ? c00w*w00 : 0.f);
        *(float4*)(cb_s + prl*CAP + pcb) = make_float4(
            v0 ? c01x*w01 : 0.f, v1 ? c01y*w01 : 0.f,
            v2 ? c01z*w01 : 0.f, v3 ? c01w*w01 : 0.f);
        *(float4*)(cc_s + prl*CAP + pcb) = make_float4(
            v0 ? c10x*w10 : 0.f, v1 ? c10y*w10 : 0.f,
            v2 ? c10z*w10 : 0.f, v3 ? c10w*w10 : 0.f);
    }
    __syncthreads();   // also protects RS* overlay of rs/rt

    // ---- P4: row-gather partials, 4 consecutive qw per item (b128 windows)
#define P4J(A0_,A1_,A2_,A3_, B0_,B1_,B2_,B3_, C0_,C1_,C2_,C3_, SE,SO,TE,TO)   \
    SE = fmaf(A0_,d0_6, fmaf(B0_,d1_6, fmaf(A1_,d0_4, fmaf(B1_,d1_4,          \
         fmaf(A2_,d0_2, fmaf(B2_,d1_2, fmaf(A3_,d0_0, (B3_)*d1_0)))))));      \
    SO = fmaf(A0_,d0_7, fmaf(B0_,d1_7, fmaf(A1_,d0_5, fmaf(B1_,d1_5,          \
         fmaf(A2_,d0_3, fmaf(B2_,d1_3, fmaf(A3_,d0_1, (B3_)*d1_1)))))));      \
    TE = fmaf(C0_,d0_6, fmaf(C1_,d0_4, fmaf(C2_,d0_2, (C3_)*d0_0)));          \
    TO = fmaf(C0_,d0_7, fmaf(C1_,d0_5, fmaf(C2_,d0_3, (C3_)*d0_1)));
    for (int i = tid; i < PT * 7; i += NTHR) {
        int pr = i / 7;
        int qg = i - pr * 7;
        int qw0 = 4 * qg;
        int base = pr * CAP + qw0;
        float4 A0 = *(const float4*)(ca_s + base);
        float4 A1 = *(const float4*)(ca_s + base + 4);
        float4 B0 = *(const float4*)(cb_s + base);
        float4 B1 = *(const float4*)(cb_s + base + 4);
        float4 C0 = *(const float4*)(cc_s + base);
        float4 C1 = *(const float4*)(cc_s + base + 4);
        float a0=A0.x,a1=A0.y,a2=A0.z,a3=A0.w,a4=A1.x,a5=A1.y,a6=A1.z;
        float b0=B0.x,b1=B0.y,b2=B0.z,b3=B0.w,b4=B1.x,b5=B1.y,b6=B1.z;
        float c0=C0.x,c1=C0.y,c2=C0.z,c3=C0.w,c4=C1.x,c5=C1.y,c6=C1.z;
        float se0,so0,te0,to0, se1,so1,te1,to1;
        float se2,so2,te2,to2, se3,so3,te3,to3;
        P4J(a0,a1,a2,a3, b0,b1,b2,b3, c0,c1,c2,c3, se0,so0,te0,to0)
        P4J(a1,a2,a3,a4, b1,b2,b3,b4, c1,c2,c3,c4, se1,so1,te1,to1)
        P4J(a2,a3,a4,a5, b2,b3,b4,b5, c2,c3,c4,c5, se2,so2,te2,to2)
        P4J(a3,a4,a5,a6, b3,b4,b5,b6, c3,c4,c5,c6, se3,so3,te3,to3)
        int o = pr * QT + qw0;
        *(float4*)(RSe + o) = make_float4(se0, se1, se2, se3);
        *(float4*)(RSo + o) = make_float4(so0, so1, so2, so3);
        *(float4*)(RTe + o) = make_float4(te0, te1, te2, te3);
        *(float4*)(RTo + o) = make_float4(to0, to1, to2, to3);
    }
#undef P4J
    __syncthreads();

    // ---- P5: quads, 4 consecutive qwl per item (b128 rows)
    const int qh0 = h0 >> 1, qw0g = w0 >> 1;
    float* ob = out + (size_t)bc * NPIX;
    for (int i = tid; i < QT * 7; i += NTHR) {
        int qhl = i / 7;
        int qg  = i - qhl * 7;
        int qwl0 = 4 * qg;
        float aee0=0.f,aee1=0.f,aee2=0.f,aee3=0.f;
        float aeo0=0.f,aeo1=0.f,aeo2=0.f,aeo3=0.f;
        float aoe0=0.f,aoe1=0.f,aoe2=0.f,aoe3=0.f;
        float aoo0=0.f,aoo1=0.f,aoo2=0.f,aoo3=0.f;
#define P5R(kr, ie, io)                                                        \
        {                                                                      \
            const int o = (qhl + (kr)) * QT + qwl0;                            \
            const float4 SE = *(const float4*)(RSe + o);                       \
            const float4 SO = *(const float4*)(RSo + o);                       \
            const float4 TE = *(const float4*)(RTe + o);                       \
            const float4 TO = *(const float4*)(RTo + o);                       \
            aee0 = fmaf(d0_##ie, SE.x, fmaf(d1_##ie, TE.x, aee0));             \
            aee1 = fmaf(d0_##ie, SE.y, fmaf(d1_##ie, TE.y, aee1));             \
            aee2 = fmaf(d0_##ie, SE.z, fmaf(d1_##ie, TE.z, aee2));             \
            aee3 = fmaf(d0_##ie, SE.w, fmaf(d1_##ie, TE.w, aee3));             \
            aeo0 = fmaf(d0_##ie, SO.x, fmaf(d1_##ie, TO.x, aeo0));             \
            aeo1 = fmaf(d0_##ie, SO.y, fmaf(d1_##ie, TO.y, aeo1));             \
            aeo2 = fmaf(d0_##ie, SO.z, fmaf(d1_##ie, TO.z, aeo2));             \
            aeo3 = fmaf(d0_##ie, SO.w, fmaf(d1_##ie, TO.w, aeo3));             \
            aoe0 = fmaf(d0_##io, SE.x, fmaf(d1_##io, TE.x, aoe0));             \
            aoe1 = fmaf(d0_##io, SE.y, fmaf(d1_##io, TE.y, aoe1));             \
            aoe2 = fmaf(d0_##io, SE.z, fmaf(d1_##io, TE.z, aoe2));             \
            aoe3 = fmaf(d0_##io, SE.w, fmaf(d1_##io, TE.w, aoe3));             \
            aoo0 = fmaf(d0_##io, SO.x, fmaf(d1_##io, TO.x, aoo0));             \
            aoo1 = fmaf(d0_##io, SO.y, fmaf(d1_##io, TO.y, aoo1));             \
            aoo2 = fmaf(d0_##io, SO.z, fmaf(d1_##io, TO.z, aoo2));             \
            aoo3 = fmaf(d0_##io, SO.w, fmaf(d1_##io, TO.w, aoo3));             \
        }
        P5R(0, 6, 7) P5R(1, 4, 5) P5R(2, 2, 3) P5R(3, 0, 1)
#undef P5R

        int qh  = qh0 + qhl;
        int nvr = min(qh, NP - 1) - max(qh - 3, 0) + 1;
        int qwg = qw0g + qwl0;
        float cn0 = (float)(nvr * (min(qwg+0, NP-1) - max(qwg+0-3, 0) + 1));
        float cn1 = (float)(nvr * (min(qwg+1, NP-1) - max(qwg+1-3, 0) + 1));
        float cn2 = (float)(nvr * (min(qwg+2, NP-1) - max(qwg+2-3, 0) + 1));
        float cn3 = (float)(nvr * (min(qwg+3, NP-1) - max(qwg+3-3, 0) + 1));

        // identity term: quad pixels at staged rows 2qhl+6/7, cols qwl0+3+j
        const int xi = (2*qhl + 6) * XCP + (qwl0 + 3);
        float x00_0 = xe_s[xi+0], x00_1 = xe_s[xi+1], x00_2 = xe_s[xi+2], x00_3 = xe_s[xi+3];
        float x01_0 = xo_s[xi+0], x01_1 = xo_s[xi+1], x01_2 = xo_s[xi+2], x01_3 = xo_s[xi+3];
        float x10_0 = xe_s[xi+XCP+0], x10_1 = xe_s[xi+XCP+1], x10_2 = xe_s[xi+XCP+2], x10_3 = xe_s[xi+XCP+3];
        float x11_0 = xo_s[xi+XCP+0], x11_1 = xo_s[xi+XCP+1], x11_2 = xo_s[xi+XCP+2], x11_3 = xo_s[xi+XCP+3];

        float4 r0a = make_float4(fmaf(cn0, x00_0, -aee0), fmaf(cn0, x01_0, -aeo0),
                                 fmaf(cn1, x00_1, -aee1), fmaf(cn1, x01_1, -aeo1));
        float4 r0b = make_float4(fmaf(cn2, x00_2, -aee2), fmaf(cn2, x01_2, -aeo2),
                                 fmaf(cn3, x00_3, -aee3), fmaf(cn3, x01_3, -aeo3));
        float4 r1a = make_float4(fmaf(cn0, x10_0, -aoe0), fmaf(cn0, x11_0, -aoo0),
                                 fmaf(cn1, x10_1, -aoe1), fmaf(cn1, x11_1, -aoo1));
        float4 r1b = make_float4(fmaf(cn2, x10_2, -aoe2), fmaf(cn2, x11_2, -aoo2),
                                 fmaf(cn3, x10_3, -aoe3), fmaf(cn3, x11_3, -aoo3));

        float* orp = ob + (size_t)(h0 + 2*qhl) * IMG + (w0 + 2*qwl0);
        *(float4*)(orp)           = r0a;
        *(float4*)(orp + 4)       = r0b;
        *(float4*)(orp + IMG)     = r1a;
        *(float4*)(orp + IMG + 4) = r1b;
    }
}

extern "C" void kernel_launch(void* const* d_in, const int* in_sizes, int n_in,
                              void* d_out, int out_size, void* d_ws, size_t ws_size,
                              hipStream_t stream)
{
    const float* x    = (const float*)d_in[0];
    const float* D    = (const float*)d_in[1];
    const float* filt = (const float*)d_in[2];
    float* out        = (float*)d_out;

    dim3 grid(IMG / TILE, IMG / TILE, BC);   // 4 x 4 x 48 = 768 workgroups
    fused_dct_kernel<<<grid, NTHR, 0, stream>>>(x, D, filt, out);
    (void)d_ws; (void)ws_size;               // workspace intentionally unused
}